// Round 2
// baseline (18149.179 us; speedup 1.0000x reference)
//
#include <hip/hip_runtime.h>
#include <math.h>

// Problem constants (V,E,H,K,T,B) = (32000, 512, 512, 32, 256, 64)
#define T_STEPS 256
#define BATCH   64
#define HID     512
#define EMB     512
#define KTAGS   32
#define GDIM    2048      // 4*HID
#define NEGV    -100000.0f
#define START_TAG 30
#define END_TAG   31

// ---------------------------------------------------------------------------
// Zero the LSTM cell-state buffer (and optionally the scalar output).
// Replaces hipMemsetAsync to stay maximally graph-capture-safe.
// ---------------------------------------------------------------------------
__global__ __launch_bounds__(256) void init_zero(float* __restrict__ cbuf,
                                                 float* __restrict__ out,
                                                 int zero_out)
{
    int i = blockIdx.x * 256 + threadIdx.x;
    const int n = 2 * BATCH * HID;
    for (; i < n; i += gridDim.x * 256) cbuf[i] = 0.0f;
    if (zero_out && blockIdx.x == 0 && threadIdx.x == 0) *out = 0.0f;
}

// ---------------------------------------------------------------------------
// One LSTM timestep, input GEMM fused:
//   g = x_t @ Wih^T + h_{t-1} @ Whh^T + b    (K = xK + 512, two staging phases)
// Grid: (nc=64 gate-col chunks, bh=2 batch halves, d=2 directions).
// Block tile: 32 batch rows x 32 gate cols (8 h-cols x 4 gates).
// Thread: 1 row x 4 cols (float4 acc); inner loop is 1 A-b128 + 4 W-b128
// per 16 FMA, conflict-free LDS layout.
// h state: hs (T,B,1024) written at tt, read at tprev (kernel boundary = sync).
// c state: cbuf[2][B][H], zeroed per layer by init_zero.
// ---------------------------------------------------------------------------
__global__ __launch_bounds__(256) void lstm_step_fused(
    const float* __restrict__ xsrc,   // [T*B][x_lda] layer input (null if embed path)
    long long x_lda,
    const int*   __restrict__ tokens, // if non-null: x row = embed[tokens[tt*B+b]]
    const float* __restrict__ embed,  // [V][EMB]
    const float* __restrict__ wih,    // [2][GDIM][xK]
    int xK,
    const float* __restrict__ whh,    // [2][GDIM][HID]
    const float* __restrict__ bias,   // [2][GDIM]
    float* __restrict__ hs,           // [T][B][1024]
    float* __restrict__ cbuf,         // [2][B][HID]
    int s)
{
    const int nc = blockIdx.x;        // 0..63 -> h-cols nc*8 .. nc*8+7
    const int bh = blockIdx.y;        // 0..1
    const int d  = blockIdx.z;        // direction
    const int tt    = d ? (T_STEPS - 1 - s) : s;
    const int tprev = d ? (tt + 1) : (tt - 1);
    const int tid = threadIdx.x;

    __shared__ __align__(16) float As[32][68];   // [b][k] tile, rows 272B (16B-mult)
    __shared__ __align__(16) float Ws[64][36];   // [k][c] tile, rows 144B
    __shared__ __align__(16) float gs[32][36];

    const int myrow = tid >> 3;       // 0..31 batch row in tile
    const int mycg  = tid & 7;        // col group: gate-cols 4*mycg..+3

    float4 acc = make_float4(0.f, 0.f, 0.f, 0.f);

    const float* wih_d = wih + (long long)d * GDIM * xK;
    const float* whh_d = whh + (long long)d * GDIM * HID;
    const int arow = tid >> 4;        // staging helpers (2 iters of +16 rows / +... )
    const int aq   = tid & 15;

    // ---------------- phase 1: input contribution (every step) -------------
    for (int k0 = 0; k0 < xK; k0 += 64) {
        // A tile: 32 rows x 64 k
        #pragma unroll
        for (int it = 0; it < 2; ++it) {
            int row = arow + it * 16;
            int b   = bh * 32 + row;
            const float* src = tokens
                ? (embed + (long long)tokens[tt * BATCH + b] * EMB)
                : (xsrc  + (long long)(tt * BATCH + b) * x_lda);
            float4 v = *(const float4*)(src + k0 + 4 * aq);
            *(float4*)&As[row][4 * aq] = v;
        }
        // W tile (transposed): 32 gate-cols x 64 k
        #pragma unroll
        for (int it = 0; it < 2; ++it) {
            int c = arow + it * 16;                    // 0..31
            int r = (c >> 3) * HID + nc * 8 + (c & 7); // gate*H + n
            float4 v = *(const float4*)(wih_d + (long long)r * xK + k0 + 4 * aq);
            Ws[4*aq+0][c] = v.x; Ws[4*aq+1][c] = v.y;
            Ws[4*aq+2][c] = v.z; Ws[4*aq+3][c] = v.w;
        }
        __syncthreads();
        #pragma unroll
        for (int kk4 = 0; kk4 < 16; ++kk4) {
            float4 av = *(const float4*)&As[myrow][4 * kk4];
            #pragma unroll
            for (int u = 0; u < 4; ++u) {
                float a = (&av.x)[u];
                float4 wv = *(const float4*)&Ws[4 * kk4 + u][4 * mycg];
                acc.x += a * wv.x; acc.y += a * wv.y;
                acc.z += a * wv.z; acc.w += a * wv.w;
            }
        }
        __syncthreads();
    }

    // ---------------- phase 2: recurrent contribution (s > 0) --------------
    if (s > 0) {
        const float* hprev = hs + (long long)tprev * (BATCH * 1024) + d * HID;
        for (int k0 = 0; k0 < HID; k0 += 64) {
            #pragma unroll
            for (int it = 0; it < 2; ++it) {
                int row = arow + it * 16;
                int b   = bh * 32 + row;
                float4 v = *(const float4*)(hprev + (long long)b * 1024 + k0 + 4 * aq);
                *(float4*)&As[row][4 * aq] = v;
            }
            #pragma unroll
            for (int it = 0; it < 2; ++it) {
                int c = arow + it * 16;
                int r = (c >> 3) * HID + nc * 8 + (c & 7);
                float4 v = *(const float4*)(whh_d + (long long)r * HID + k0 + 4 * aq);
                Ws[4*aq+0][c] = v.x; Ws[4*aq+1][c] = v.y;
                Ws[4*aq+2][c] = v.z; Ws[4*aq+3][c] = v.w;
            }
            __syncthreads();
            #pragma unroll
            for (int kk4 = 0; kk4 < 16; ++kk4) {
                float4 av = *(const float4*)&As[myrow][4 * kk4];
                #pragma unroll
                for (int u = 0; u < 4; ++u) {
                    float a = (&av.x)[u];
                    float4 wv = *(const float4*)&Ws[4 * kk4 + u][4 * mycg];
                    acc.x += a * wv.x; acc.y += a * wv.y;
                    acc.z += a * wv.z; acc.w += a * wv.w;
                }
            }
            __syncthreads();
        }
    }

    *(float4*)&gs[myrow][4 * mycg] = acc;
    __syncthreads();

    // ---------------- gate elementwise: one (b, n) per thread ---------------
    const int bi = tid >> 3, ni = tid & 7;
    const int b  = bh * 32 + bi;
    const int n  = nc * 8 + ni;
    const float* bz = bias + (long long)d * GDIM;
    float iv = gs[bi][ 0 + ni] + bz[0 * HID + n];
    float fv = gs[bi][ 8 + ni] + bz[1 * HID + n];
    float gv = gs[bi][16 + ni] + bz[2 * HID + n];
    float ov = gs[bi][24 + ni] + bz[3 * HID + n];
    long long cidx = (long long)d * BATCH * HID + (long long)b * HID + n;
    float cprev = cbuf[cidx];
    float si = 1.f / (1.f + __expf(-iv));
    float sf = 1.f / (1.f + __expf(-fv));
    float so = 1.f / (1.f + __expf(-ov));
    float cn = sf * cprev + si * tanhf(gv);
    float hn = so * tanhf(cn);
    cbuf[cidx] = cn;
    hs[(long long)tt * (BATCH * 1024) + (long long)b * 1024 + d * HID + n] = hn;
}

// ---------------------------------------------------------------------------
// Small tiled GEMM for feats:  C[m][n] = sum_k A[m][k]*W[n][k] + bias[n]
// (64x64 tile structure, N=32 guarded.)
// ---------------------------------------------------------------------------
__global__ __launch_bounds__(256) void gemm_feats(
    const float* __restrict__ A, long long lda,
    const float* __restrict__ W,      // [N][K]
    const float* __restrict__ bias,
    float* __restrict__ C,
    int M, int N, int K)
{
    __shared__ __align__(16) float As[64][34];
    __shared__ __align__(16) float Ws[32][68];

    const int m0 = blockIdx.y * 64;
    const int tid = threadIdx.x;
    const int tr = tid >> 4;
    const int tc = tid & 15;

    float acc[4][4];
    #pragma unroll
    for (int i = 0; i < 4; ++i)
        #pragma unroll
        for (int j = 0; j < 4; ++j) acc[i][j] = 0.0f;

    for (int k0 = 0; k0 < K; k0 += 32) {
        int idx = tid;
        #pragma unroll
        for (int it = 0; it < 2; ++it) {
            int row = idx >> 3;
            int q   = idx & 7;
            float4 v = *(const float4*)(A + (long long)(m0 + row) * lda + k0 + 4*q);
            As[row][4*q+0] = v.x; As[row][4*q+1] = v.y;
            As[row][4*q+2] = v.z; As[row][4*q+3] = v.w;
            idx += 256;
        }
        idx = tid;
        #pragma unroll
        for (int it = 0; it < 2; ++it) {
            int row = idx >> 3;
            int q   = idx & 7;
            float4 v = make_float4(0.f, 0.f, 0.f, 0.f);
            if (row < N)
                v = *(const float4*)(W + (long long)row * K + k0 + 4*q);
            Ws[4*q+0][row] = v.x; Ws[4*q+1][row] = v.y;
            Ws[4*q+2][row] = v.z; Ws[4*q+3][row] = v.w;
            idx += 256;
        }
        __syncthreads();
        #pragma unroll 8
        for (int kk = 0; kk < 32; ++kk) {
            float a0 = As[4*tr+0][kk], a1 = As[4*tr+1][kk];
            float a2 = As[4*tr+2][kk], a3 = As[4*tr+3][kk];
            float4 wv = *(const float4*)&Ws[kk][4*tc];
            acc[0][0] += a0*wv.x; acc[0][1] += a0*wv.y; acc[0][2] += a0*wv.z; acc[0][3] += a0*wv.w;
            acc[1][0] += a1*wv.x; acc[1][1] += a1*wv.y; acc[1][2] += a1*wv.z; acc[1][3] += a1*wv.w;
            acc[2][0] += a2*wv.x; acc[2][1] += a2*wv.y; acc[2][2] += a2*wv.z; acc[2][3] += a2*wv.w;
            acc[3][0] += a3*wv.x; acc[3][1] += a3*wv.y; acc[3][2] += a3*wv.z; acc[3][3] += a3*wv.w;
        }
        __syncthreads();
    }
    #pragma unroll
    for (int i = 0; i < 4; ++i) {
        int m = m0 + 4*tr + i;
        #pragma unroll
        for (int j = 0; j < 4; ++j) {
            int n = 4*tc + j;
            if (n < N) C[(long long)m * N + n] = acc[i][j] + bias[n];
        }
    }
}

// ---------------------------------------------------------------------------
// CRF: forward logsumexp scan + log_z + gold score + loss, one block per b.
// ---------------------------------------------------------------------------
__global__ __launch_bounds__(1024) void crf_kernel(
    const float* __restrict__ feats,   // [T*B][K]
    const float* __restrict__ trans,   // [K][K]
    const int*   __restrict__ tokens,  // [T*B]
    const int*   __restrict__ tags,    // [T*B]
    const int*   __restrict__ lengths, // [B]
    float* __restrict__ out)
{
    const int b = blockIdx.x;
    const int tid = threadIdx.x;
    __shared__ float tr_s[KTAGS*KTAGS];
    __shared__ float score_s[KTAGS];
    __shared__ float emit_s[KTAGS];
    __shared__ float red_s[16];
    __shared__ float logz_s;

    tr_s[tid] = trans[tid];            // 1024 == 32*32 exactly
    if (tid < KTAGS) score_s[tid] = (tid == START_TAG) ? 0.0f : NEGV;
    __syncthreads();

    const int i = tid >> 5, j = tid & 31;
    for (int t = 0; t < T_STEPS; ++t) {
        if (tid < KTAGS) emit_s[tid] = feats[((long long)t*BATCH + b)*KTAGS + tid];
        __syncthreads();
        float e = score_s[j] + tr_s[i*KTAGS + j];
        float m = e;
        m = fmaxf(m, __shfl_xor(m, 1));  m = fmaxf(m, __shfl_xor(m, 2));
        m = fmaxf(m, __shfl_xor(m, 4));  m = fmaxf(m, __shfl_xor(m, 8));
        m = fmaxf(m, __shfl_xor(m, 16));
        float p = __expf(e - m);
        p += __shfl_xor(p, 1); p += __shfl_xor(p, 2); p += __shfl_xor(p, 4);
        p += __shfl_xor(p, 8); p += __shfl_xor(p, 16);
        float nv = m + __logf(p) + emit_s[i];
        int msk = tokens[(long long)t*BATCH + b] > 0;
        __syncthreads();
        if (j == 0) score_s[i] = msk ? nv : score_s[i];
        __syncthreads();
    }

    if (tid < KTAGS) {
        float v = score_s[tid] + tr_s[END_TAG*KTAGS + tid];
        float m = v;
        m = fmaxf(m, __shfl_xor(m, 1));  m = fmaxf(m, __shfl_xor(m, 2));
        m = fmaxf(m, __shfl_xor(m, 4));  m = fmaxf(m, __shfl_xor(m, 8));
        m = fmaxf(m, __shfl_xor(m, 16));
        float p = __expf(v - m);
        p += __shfl_xor(p, 1); p += __shfl_xor(p, 2); p += __shfl_xor(p, 4);
        p += __shfl_xor(p, 8); p += __shfl_xor(p, 16);
        if (tid == 0) logz_s = m + __logf(p);
    }
    __syncthreads();

    float val = 0.0f;
    if (tid < T_STEPS) {
        int t = tid;
        int cur  = tags[(long long)t*BATCH + b];
        int prev = (t == 0) ? START_TAG : tags[(long long)(t-1)*BATCH + b];
        int msk  = tokens[(long long)t*BATCH + b] > 0;
        if (msk) val = tr_s[cur*KTAGS + prev]
                     + feats[((long long)t*BATCH + b)*KTAGS + cur];
    }
    val += __shfl_xor(val, 1);  val += __shfl_xor(val, 2);
    val += __shfl_xor(val, 4);  val += __shfl_xor(val, 8);
    val += __shfl_xor(val, 16); val += __shfl_xor(val, 32);
    int wave = tid >> 6, lane = tid & 63;
    if (lane == 0) red_s[wave] = val;
    __syncthreads();
    if (tid == 0) {
        float g = 0.0f;
        #pragma unroll
        for (int w = 0; w < 16; ++w) g += red_s[w];
        g += tr_s[END_TAG*KTAGS + tags[(long long)(T_STEPS-1)*BATCH + b]];
        atomicAdd(out, (logz_s - g) / (float)lengths[b]);
    }
}

// ---------------------------------------------------------------------------
extern "C" void kernel_launch(void* const* d_in, const int* in_sizes, int n_in,
                              void* d_out, int out_size, void* d_ws, size_t ws_size,
                              hipStream_t stream) {
    const int*   tokens  = (const int*)  d_in[0];
    const int*   tags    = (const int*)  d_in[1];
    const int*   lengths = (const int*)  d_in[2];
    const float* embed   = (const float*)d_in[3];
    const float* wih0    = (const float*)d_in[4];
    const float* whh0    = (const float*)d_in[5];
    const float* b0      = (const float*)d_in[6];
    const float* wih1    = (const float*)d_in[7];
    const float* whh1    = (const float*)d_in[8];
    const float* b1      = (const float*)d_in[9];
    const float* lin_w   = (const float*)d_in[10];
    const float* lin_b   = (const float*)d_in[11];
    const float* trans   = (const float*)d_in[12];

    // Workspace layout (total 136,577,024 B ~= 130.3 MiB)
    char*  ws    = (char*)d_ws;
    float* hs0   = (float*)(ws);                        // 16384*1024*4 = 67108864
    float* hs1   = (float*)(ws + 67108864ULL);          //                67108864
    float* feats = (float*)(ws + 134217728ULL);         // 16384*32*4   =  2097152
    float* cbuf  = (float*)(ws + 136314880ULL);         // 2*64*512*4   =   262144

    float* out = (float*)d_out;

    // Layer 0: x = embed[tokens], xK = 512
    init_zero<<<dim3(64), 256, 0, stream>>>(cbuf, out, 1);
    for (int s = 0; s < T_STEPS; ++s)
        lstm_step_fused<<<dim3(64, 2, 2), 256, 0, stream>>>(
            nullptr, (long long)EMB, tokens, embed,
            wih0, EMB, whh0, b0, hs0, cbuf, s);

    // Layer 1: x = hs0 (T,B,1024), xK = 1024
    init_zero<<<dim3(64), 256, 0, stream>>>(cbuf, out, 0);
    for (int s = 0; s < T_STEPS; ++s)
        lstm_step_fused<<<dim3(64, 2, 2), 256, 0, stream>>>(
            hs0, (long long)(2*HID), nullptr, nullptr,
            wih1, 2*HID, whh1, b1, hs1, cbuf, s);

    // feats = hs1 @ lin_w^T + lin_b
    gemm_feats<<<dim3(1, 256, 1), 256, 0, stream>>>(
        hs1, (long long)(2*HID), lin_w, lin_b, feats,
        T_STEPS*BATCH, KTAGS, 2*HID);

    crf_kernel<<<dim3(BATCH), 1024, 0, stream>>>(feats, trans, tokens, tags,
                                                 lengths, out);
}